// Round 5
// baseline (891.979 us; speedup 1.0000x reference)
//
#include <hip/hip_runtime.h>

// SelfAttention: B=4, L=4096, H=256, fp32 in/out.
// Round 5: concurrency round — 12 waves/CU everywhere.
//  - attn: split-K x3 across blocks (grid 768 = 3 blocks/CU exactly), LDS 37 KB
//    via 16-key tile pairs (2 x 16 KB buffers, 1 barrier each); softmax/PV stay
//    at 32-key granularity. launch_bounds(256,3). Reg-prefetch keeps global
//    latency hidden.
//  - qkv: NO W LDS — wsplit emits W fragment-linear; qkv reads B-frags as
//    coalesced 1 KB L1/L2 loads (W = 0.4 MB, L2-resident). LDS = 18.4 KB
//    epilogue scratch only -> (256,3) = 3 blocks/CU.
// Precision unchanged: split-bf16 3-product QK, bf16 PV, bf16 O-partials
// (measured absmax 0.25 @ threshold 1.01).

typedef __bf16 bf16x8 __attribute__((ext_vector_type(8)));
typedef __bf16 bf16x4 __attribute__((ext_vector_type(4)));
typedef float floatx4 __attribute__((ext_vector_type(4)));

#define MFMA16(a, b, c) __builtin_amdgcn_mfma_f32_16x16x32_bf16(a, b, c, 0, 0, 0)

#define HID 256
#define LSEQ 4096
#define NB 4
#define NTOK (NB * LSEQ)             // 16384
#define PLANE ((size_t)NTOK * HID)   // 4,194,304 elements
#define QSCALE 0.09016844005556021f  // log2(e)/16 ; softmax uses exp2

// Layouts:
//  Whf/Wlf [w(3)][ct(16)][kc(8)][lane(64)][j(8)] : B-frag-linear weights.
//    element = W[h = kc*32 + (lane>>4)*8 + j][n = ct*16 + (lane&15)]
//  Kf (16-key tiles, T = tok>>4, 1024 tiles): [T][plane(hi/lo)][kc(8)][lane][j]
//    element = K(hi/lo)[key = T*16 + (lane&15)][h = kc*32 + (lane>>4)*8 + j]
//    tile stride 8192 el (16 KB), plane stride 4096, kc stride 512.
//  Vf (32-key tiles, T = tok>>5, 512 tiles): [T][dt(16)][lane][j], stride 8192.
//    element = V[key = T*32 + (lane>>4)*8 + j][d = dt*16 + (lane&15)]

__device__ __forceinline__ void split_bf16(float v, __bf16 &h, __bf16 &l) {
  h = (__bf16)v;
  l = (__bf16)(v - (float)h);
}

// ---------------------------------------------------------------------------
// Kernel 1: hi/lo-split weights -> fragment-linear Whf/Wlf.
// ---------------------------------------------------------------------------
__global__ __launch_bounds__(256) void wsplit(const float *__restrict__ Wq,
                                              const float *__restrict__ Wk,
                                              const float *__restrict__ Wv,
                                              __bf16 *__restrict__ Whf,
                                              __bf16 *__restrict__ Wlf) {
  __shared__ float tile[32][256];
  const int wsel = blockIdx.x;
  const float *W = (wsel == 0) ? Wq : (wsel == 1) ? Wk : Wv;
  const int t = threadIdx.x;
  for (int hb = 0; hb < 8; ++hb) {   // hb == kc chunk of 32 h-rows
    __syncthreads();
    #pragma unroll
    for (int p = 0; p < 8; ++p) {
      int r = p * 4 + (t >> 6);
      int c = (t & 63) * 4;
      *(floatx4 *)&tile[r][c] = *(const floatx4 *)&W[(hb * 32 + r) * HID + c];
    }
    __syncthreads();
    #pragma unroll
    for (int i = 0; i < 4; ++i) {    // 1024 (ct,lane) chunks
      const int c = i * 256 + t;
      const int lane_f = c & 63;
      const int ct = c >> 6;
      const int qf = lane_f >> 4;
      const int lnf = lane_f & 15;
      bf16x8 hh, ll;
      #pragma unroll
      for (int j = 0; j < 8; ++j) {
        float v = tile[qf * 8 + j][ct * 16 + lnf];
        __bf16 h, l;
        split_bf16(v, h, l);
        hh[j] = h; ll[j] = l;
      }
      const size_t dst = ((size_t)(wsel * 16 + ct) * 8 + hb) * 512 + lane_f * 8;
      *(bf16x8 *)&Whf[dst] = hh;
      *(bf16x8 *)&Wlf[dst] = ll;
    }
  }
}

// ---------------------------------------------------------------------------
// Kernel 2: QKV projection, LDS-free GEMM (W frags coalesced from L1/L2).
// grid = (256 m-tiles of 64 tokens, 4 col-tiles of 64), 256 thr, 3 blocks/CU.
// Epilogues: Q row-major hi/lo; K -> 16-key frag-linear; V -> 32-key frag-linear
// (both via 18.4 KB LDS scratch transpose).
// ---------------------------------------------------------------------------
__global__ __launch_bounds__(256, 3) void qkv_proj(const float *__restrict__ X,
                                                   const __bf16 *__restrict__ Whf,
                                                   const __bf16 *__restrict__ Wlf,
                                                   __bf16 *__restrict__ Qh, __bf16 *__restrict__ Ql,
                                                   __bf16 *__restrict__ Kf,
                                                   __bf16 *__restrict__ Vf) {
  __shared__ __bf16 scr[2][64 * 72];  // Th=scr[0], Tl=scr[1]; Tv aliases scr[0]

  const int mtile = blockIdx.x;
  const int col0 = blockIdx.y * 64;
  const int tid = threadIdx.x;
  const int w4 = tid >> 6;
  const int lane = tid & 63;
  const int quad = lane >> 4;
  const int ln = lane & 15;
  const int arow = mtile * 64 + w4 * 16 + ln;

  // A-frags once: 8 k-chunks of X row, hi/lo split.
  bf16x8 ah[8], al[8];
  #pragma unroll
  for (int kc = 0; kc < 8; ++kc) {
    const float *xp = X + (size_t)arow * HID + kc * 32 + quad * 8;
    floatx4 x0 = *(const floatx4 *)xp;
    floatx4 x1 = *(const floatx4 *)(xp + 4);
    #pragma unroll
    for (int j = 0; j < 4; ++j) {
      __bf16 h, l;
      split_bf16(x0[j], h, l); ah[kc][j] = h; al[kc][j] = l;
      split_bf16(x1[j], h, l); ah[kc][4 + j] = h; al[kc][4 + j] = l;
    }
  }

  for (int w = 0; w < 3; ++w) {
    floatx4 acc[4] = {};
    #pragma unroll
    for (int kc = 0; kc < 8; ++kc) {
      #pragma unroll
      for (int nt = 0; nt < 4; ++nt) {
        const size_t wo = ((size_t)(w * 16 + (col0 >> 4) + nt) * 8 + kc) * 512 + lane * 8;
        bf16x8 bh = *(const bf16x8 *)&Whf[wo];
        bf16x8 bl = *(const bf16x8 *)&Wlf[wo];
        acc[nt] = MFMA16(ah[kc], bh, acc[nt]);
        acc[nt] = MFMA16(ah[kc], bl, acc[nt]);
        acc[nt] = MFMA16(al[kc], bh, acc[nt]);
      }
    }

    // Epilogues. C/D layout: col = lane&15, row = quad*4 + reg.
    if (w == 0) {
      #pragma unroll
      for (int nt = 0; nt < 4; ++nt) {
        #pragma unroll
        for (int r = 0; r < 4; ++r) {
          float v = acc[nt][r] * QSCALE;
          __bf16 h, l;
          split_bf16(v, h, l);
          const int orow = mtile * 64 + w4 * 16 + quad * 4 + r;
          const int ocol = col0 + nt * 16 + ln;
          Qh[(size_t)orow * HID + ocol] = h;
          Ql[(size_t)orow * HID + ocol] = l;
        }
      }
    } else if (w == 1) {
      __syncthreads();
      #pragma unroll
      for (int nt = 0; nt < 4; ++nt) {
        #pragma unroll
        for (int r = 0; r < 4; ++r) {
          __bf16 h, l;
          split_bf16(acc[nt][r], h, l);
          const int tok_l = w4 * 16 + quad * 4 + r;
          const int h_l = nt * 16 + ln;
          scr[0][tok_l * 72 + h_l] = h;
          scr[1][tok_l * 72 + h_l] = l;
        }
      }
      __syncthreads();
      #pragma unroll
      for (int i = 0; i < 2; ++i) {     // 512 chunks: 4 t4 x 2 kcL x 64 lanes
        const int c = i * 256 + tid;
        const int lane_f = c & 63;
        const int kcL = (c >> 6) & 1;
        const int t4 = (c >> 7) & 3;
        const int qf = lane_f >> 4;
        const int lnf = lane_f & 15;
        bf16x8 vh = *(const bf16x8 *)&scr[0][(t4 * 16 + lnf) * 72 + kcL * 32 + qf * 8];
        bf16x8 vl = *(const bf16x8 *)&scr[1][(t4 * 16 + lnf) * 72 + kcL * 32 + qf * 8];
        const int T = mtile * 4 + t4;
        const int kc = (col0 >> 5) + kcL;
        *(bf16x8 *)&Kf[((size_t)(T * 2 + 0) * 8 + kc) * 512 + lane_f * 8] = vh;
        *(bf16x8 *)&Kf[((size_t)(T * 2 + 1) * 8 + kc) * 512 + lane_f * 8] = vl;
      }
    } else {
      __syncthreads();  // w==1 scratch reads done before clobber
      #pragma unroll
      for (int nt = 0; nt < 4; ++nt) {
        #pragma unroll
        for (int r = 0; r < 4; ++r) {
          const int tok_l = w4 * 16 + quad * 4 + r;
          const int d_l = nt * 16 + ln;
          scr[0][d_l * 72 + tok_l] = (__bf16)acc[nt][r];
        }
      }
      __syncthreads();
      #pragma unroll
      for (int i = 0; i < 2; ++i) {     // 512 chunks: 2 t2 x 4 dtL x 64 lanes
        const int c = i * 256 + tid;
        const int lane_f = c & 63;
        const int dtL = (c >> 6) & 3;
        const int t2 = (c >> 8) & 1;
        const int qf = lane_f >> 4;
        const int lnf = lane_f & 15;
        bf16x8 v = *(const bf16x8 *)&scr[0][(dtL * 16 + lnf) * 72 + t2 * 32 + qf * 8];
        const int T = mtile * 2 + t2;
        const int dt = (col0 >> 4) + dtL;
        *(bf16x8 *)&Vf[(size_t)(T * 16 + dt) * 512 + lane_f * 8] = v;
      }
    }
  }
}

// ---------------------------------------------------------------------------
// Kernel 3: flash attention, split-K x nks (3 default), 16-key tile pairs.
// grid = 256*nks blocks (qt = bx/nks, ks = bx%nks), 256 thr, 3 blocks/CU.
// LDS 37 KB: KS[2][8192] (two 16-key hi+lo tiles) + PsS. One barrier per tile;
// softmax/PV at 32-key granularity. Buffer hazards: writer of KS[p] passed the
// opposite-stage barrier, which every wave crosses only after its own read of
// KS[p] -> safe without extra barriers.
// ---------------------------------------------------------------------------
__global__ __launch_bounds__(256, 3) void attn(const __bf16 *__restrict__ QhG,
                                               const __bf16 *__restrict__ QlG,
                                               const __bf16 *__restrict__ Kf,
                                               const __bf16 *__restrict__ Vf,
                                               __bf16 *__restrict__ Op,
                                               float *__restrict__ Mp,
                                               float *__restrict__ Lp,
                                               int nks) {
  __shared__ __bf16 KS[2][8192];
  __shared__ __bf16 PsS[4 * 16 * 40];

  const int bx = blockIdx.x;
  const int ks = bx % nks;
  const int qt = bx / nks;        // 0..255
  const int b = qt >> 6;
  const int qtl = qt & 63;
  const int tid = threadIdx.x;
  const int w4 = tid >> 6;
  const int lane = tid & 63;
  const int quad = lane >> 4;
  const int ln = lane & 15;

  // 16-key-tile range for this ks (per batch: 256 tiles). Even-length thirds.
  int ts, te;
  if (nks == 2) { ts = ks * 128; te = ts + 128; }
  else          { ts = (ks == 0) ? 0 : (ks == 1 ? 86 : 172);
                  te = (ks == 0) ? 86 : (ks == 1 ? 172 : 256); }
  const int nmac = (te - ts) >> 1;   // 32-key macro iterations

  // Q frags (hi+lo), once.
  const int qtok = b * LSEQ + qtl * 64 + w4 * 16 + ln;
  bf16x8 qh[8], ql[8];
  #pragma unroll
  for (int kc = 0; kc < 8; ++kc) {
    const size_t off = (size_t)qtok * HID + kc * 32 + quad * 8;
    qh[kc] = *(const bf16x8 *)&QhG[off];
    ql[kc] = *(const bf16x8 *)&QlG[off];
  }

  const __bf16 *kfb = Kf + (size_t)(b * 256 + ts) * 8192 + tid * 8;
  const __bf16 *vfb = Vf + (size_t)(b * 128 + (ts >> 1)) * 8192 + lane * 8;

  // Prefetch first tile pair into regs (64 B/thread per tile).
  bf16x8 g0[4], g1[4];
  #pragma unroll
  for (int i = 0; i < 4; ++i) {
    g0[i] = *(const bf16x8 *)&kfb[i * 2048];
    g1[i] = *(const bf16x8 *)&kfb[8192 + i * 2048];
  }

  float m[4] = {-1e30f, -1e30f, -1e30f, -1e30f};
  float l[4] = {0.f, 0.f, 0.f, 0.f};
  floatx4 o[16] = {};

  for (int j = 0; j < nmac; ++j) {
    // ---- stage tile 2j -> KS[0] (linear, conflict-free) ----
    #pragma unroll
    for (int i = 0; i < 4; ++i) *(bf16x8 *)&KS[0][i * 2048 + tid * 8] = g0[i];
    __syncthreads();
    if (j + 1 < nmac) {
      const __bf16 *src = kfb + (size_t)(2 * j + 2) * 8192;
      #pragma unroll
      for (int i = 0; i < 4; ++i) g0[i] = *(const bf16x8 *)&src[i * 2048];
    }
    // ---- QK on keys [32j, 32j+16) ----
    floatx4 s[2] = {};
    #pragma unroll
    for (int kc = 0; kc < 8; ++kc) {
      bf16x8 bh = *(const bf16x8 *)&KS[0][kc * 512 + lane * 8];
      bf16x8 bl = *(const bf16x8 *)&KS[0][4096 + kc * 512 + lane * 8];
      s[0] = MFMA16(qh[kc], bh, s[0]);
      s[0] = MFMA16(qh[kc], bl, s[0]);
      s[0] = MFMA16(ql[kc], bh, s[0]);
    }
    // V batch 1 (direct global, frag-linear)
    const __bf16 *vsrc = vfb + (size_t)j * 8192;
    bf16x8 vb0[8];
    #pragma unroll
    for (int dt = 0; dt < 8; ++dt) vb0[dt] = *(const bf16x8 *)&vsrc[dt * 512];

    // ---- stage tile 2j+1 -> KS[1] ----
    #pragma unroll
    for (int i = 0; i < 4; ++i) *(bf16x8 *)&KS[1][i * 2048 + tid * 8] = g1[i];
    __syncthreads();
    if (j + 1 < nmac) {
      const __bf16 *src = kfb + (size_t)(2 * j + 3) * 8192;
      #pragma unroll
      for (int i = 0; i < 4; ++i) g1[i] = *(const bf16x8 *)&src[i * 2048];
    }
    // ---- QK on keys [32j+16, 32j+32) ----
    #pragma unroll
    for (int kc = 0; kc < 8; ++kc) {
      bf16x8 bh = *(const bf16x8 *)&KS[1][kc * 512 + lane * 8];
      bf16x8 bl = *(const bf16x8 *)&KS[1][4096 + kc * 512 + lane * 8];
      s[1] = MFMA16(qh[kc], bh, s[1]);
      s[1] = MFMA16(qh[kc], bl, s[1]);
      s[1] = MFMA16(ql[kc], bh, s[1]);
    }
    // V batch 2
    bf16x8 vb1[8];
    #pragma unroll
    for (int dt = 0; dt < 8; ++dt) vb1[dt] = *(const bf16x8 *)&vsrc[(8 + dt) * 512];

    // ---- online softmax over the 32-key pair (base-2) ----
    float alpha[4];
    #pragma unroll
    for (int r = 0; r < 4; ++r) {
      float tmax = fmaxf(s[0][r], s[1][r]);
      #pragma unroll
      for (int d = 1; d < 16; d <<= 1) tmax = fmaxf(tmax, __shfl_xor(tmax, d));
      const float mn = fmaxf(m[r], tmax);
      const float al = exp2f(m[r] - mn);
      const float p0 = exp2f(s[0][r] - mn);
      const float p1 = exp2f(s[1][r] - mn);
      s[0][r] = p0; s[1][r] = p1;
      float rs = p0 + p1;
      #pragma unroll
      for (int d = 1; d < 16; d <<= 1) rs += __shfl_xor(rs, d);
      l[r] = l[r] * al + rs;
      m[r] = mn;
      alpha[r] = al;
    }
    #pragma unroll
    for (int dt = 0; dt < 16; ++dt) {
      o[dt][0] *= alpha[0]; o[dt][1] *= alpha[1];
      o[dt][2] *= alpha[2]; o[dt][3] *= alpha[3];
    }

    // ---- P round-trip (per-wave region, same-wave: no barrier) ----
    __bf16 *ps = PsS + w4 * 16 * 40;
    #pragma unroll
    for (int nt = 0; nt < 2; ++nt)
      #pragma unroll
      for (int r = 0; r < 4; ++r)
        ps[(quad * 4 + r) * 40 + nt * 16 + ln] = (__bf16)s[nt][r];
    const bf16x8 pa = *(const bf16x8 *)&ps[ln * 40 + quad * 8];

    // ---- O += P V ----
    #pragma unroll
    for (int dt = 0; dt < 8; ++dt) o[dt] = MFMA16(pa, vb0[dt], o[dt]);
    #pragma unroll
    for (int dt = 0; dt < 8; ++dt) o[8 + dt] = MFMA16(pa, vb1[dt], o[8 + dt]);
  }

  // ---- partials: unnormalized O (bf16) + m/l (fp32) ----
  const int rowbase = b * LSEQ + qtl * 64 + w4 * 16 + quad * 4;
  #pragma unroll
  for (int dt = 0; dt < 16; ++dt)
    #pragma unroll
    for (int r = 0; r < 4; ++r)
      Op[(size_t)ks * PLANE + (size_t)(rowbase + r) * HID + dt * 16 + ln] = (__bf16)o[dt][r];
  if (ln == 0) {
    #pragma unroll
    for (int r = 0; r < 4; ++r) {
      Mp[ks * NTOK + rowbase + r] = m[r];
      Lp[ks * NTOK + rowbase + r] = l[r];
    }
  }
}

// ---------------------------------------------------------------------------
// Kernel 4: split-K merge over nks partials.
// ---------------------------------------------------------------------------
__global__ __launch_bounds__(256) void merge(const __bf16 *__restrict__ Op,
                                             const float *__restrict__ Mp,
                                             const float *__restrict__ Lp,
                                             float *__restrict__ Out, int nks) {
  const int row = blockIdx.x * 4 + (threadIdx.x >> 6);
  const int c = (threadIdx.x & 63) * 4;
  float M = -1e30f;
  for (int i = 0; i < nks; ++i) M = fmaxf(M, Mp[i * NTOK + row]);
  float L = 0.f;
  for (int i = 0; i < nks; ++i) L += Lp[i * NTOK + row] * exp2f(Mp[i * NTOK + row] - M);
  const float invL = 1.0f / L;
  floatx4 out = {};
  for (int i = 0; i < nks; ++i) {
    const float w = exp2f(Mp[i * NTOK + row] - M) * invL;
    bf16x4 a = *(const bf16x4 *)&Op[i * PLANE + (size_t)row * HID + c];
    #pragma unroll
    for (int j = 0; j < 4; ++j) out[j] += w * (float)a[j];
  }
  *(floatx4 *)&Out[(size_t)row * HID + c] = out;
}

// ---------------------------------------------------------------------------
extern "C" void kernel_launch(void *const *d_in, const int *in_sizes, int n_in,
                              void *d_out, int out_size, void *d_ws, size_t ws_size,
                              hipStream_t stream) {
  const float *X = (const float *)d_in[0];
  const float *Wq = (const float *)d_in[1];
  const float *Wk = (const float *)d_in[2];
  const float *Wv = (const float *)d_in[3];
  // d_in[4] = lengths (unused by reference)

  const size_t WFRAG = (size_t)3 * 16 * 8 * 512;  // 196608 el per plane
  // ws need (bytes): 5 planes bf16 + 2 W planes + nks*(Op plane + M + L)
  auto need = [&](int nks) {
    return (5 * PLANE + 2 * WFRAG + (size_t)nks * PLANE) * 2 +
           (size_t)nks * NTOK * 8;
  };
  const int nks = (ws_size >= need(3)) ? 3 : 2;

  __bf16 *ws = (__bf16 *)d_ws;
  __bf16 *Qh = ws;                           // [16384][256] row-major
  __bf16 *Ql = Qh + PLANE;
  __bf16 *Kf = Ql + PLANE;                   // 16-key frag-linear, 2*PLANE
  __bf16 *Vf = Kf + 2 * PLANE;               // 32-key frag-linear, PLANE
  __bf16 *Whf = Vf + PLANE;                  // frag-linear weights
  __bf16 *Wlf = Whf + WFRAG;
  __bf16 *Op = Wlf + WFRAG;                  // [nks][16384][256] unnormalized
  float *Mp = (float *)(Op + (size_t)nks * PLANE);
  float *Lp = Mp + (size_t)nks * NTOK;

  wsplit<<<3, 256, 0, stream>>>(Wq, Wk, Wv, Whf, Wlf);
  qkv_proj<<<dim3(256, 4), 256, 0, stream>>>(X, Whf, Wlf, Qh, Ql, Kf, Vf);
  attn<<<256 * nks, 256, 0, stream>>>(Qh, Ql, Kf, Vf, Op, Mp, Lp, nks);
  merge<<<NTOK / 4, 256, 0, stream>>>(Op, Mp, Lp, (float *)d_out, nks);
}

// Round 6
// 287.625 us; speedup vs baseline: 3.1012x; 3.1012x over previous
//
#include <hip/hip_runtime.h>

// SelfAttention: B=4, L=4096, H=256, fp32 in/out.
// Round 6: r4 skeleton (known-good: 220us attn, 128 VGPR, no spill) + serial-
// latency attack:
//  - DPP softmax: __shfl_xor was ds_swizzle (LDS pipe, ~8 dependent ops/row);
//    reduction domain = 16-lane DPP row -> row_ror 1/2/4/8 VALU rotates.
//  - QK 3-way chain split (hh/hl/lh independent accumulators, 8-deep each
//    instead of one 24-deep dependent MFMA chain).
//  - O-rescale moved between P-write and P-read to cover the LDS round-trip.
// r5 lesson: __launch_bounds__(256,3) spilled (VGPR 84, 2.7GB scratch HBM
// traffic) — 2 blocks/CU is the register-arithmetic max for this kernel.
// Precision: split-bf16 3-product QK, bf16 PV, bf16 O-partials (absmax 0.25).

typedef __bf16 bf16x8 __attribute__((ext_vector_type(8)));
typedef __bf16 bf16x4 __attribute__((ext_vector_type(4)));
typedef float floatx4 __attribute__((ext_vector_type(4)));

#define MFMA16(a, b, c) __builtin_amdgcn_mfma_f32_16x16x32_bf16(a, b, c, 0, 0, 0)

#define HID 256
#define LSEQ 4096
#define NB 4
#define NTOK (NB * LSEQ)             // 16384
#define PLANE ((size_t)NTOK * HID)   // 4,194,304 elements
#define QSCALE 0.09016844005556021f  // log2(e)/16 ; softmax uses exp2

// Fragment-linear layouts (32-key tiles, T = tok>>5, 512 tiles):
//  Kf[T][hi/lo][nt(2)][kc(8)][lane(64)][j(8)] : tile stride 16384 el
//  Vf[T][dt(16)][lane(64)][j(8)] : tile stride 8192 el

__device__ __forceinline__ void split_bf16(float v, __bf16 &h, __bf16 &l) {
  h = (__bf16)v;
  l = (__bf16)(v - (float)h);
}

// DPP 16-lane-row butterfly reductions (VALU, replaces ds_swizzle shuffles).
template <int N>
__device__ __forceinline__ float dpp_ror(float v) {
  return __builtin_bit_cast(float,
      __builtin_amdgcn_update_dpp(0, __builtin_bit_cast(int, v),
                                  0x120 + N, 0xf, 0xf, true));
}
__device__ __forceinline__ float row_sum16(float v) {
  v += dpp_ror<1>(v);
  v += dpp_ror<2>(v);
  v += dpp_ror<4>(v);
  v += dpp_ror<8>(v);
  return v;
}
__device__ __forceinline__ float row_max16(float v) {
  v = fmaxf(v, dpp_ror<1>(v));
  v = fmaxf(v, dpp_ror<2>(v));
  v = fmaxf(v, dpp_ror<4>(v));
  v = fmaxf(v, dpp_ror<8>(v));
  return v;
}

// ---------------------------------------------------------------------------
// Kernel 1: transpose + hi/lo-split weights -> Wht/Wlt [3][n][h] row-major.
// ---------------------------------------------------------------------------
__global__ __launch_bounds__(256) void wsplit(const float *__restrict__ Wq,
                                              const float *__restrict__ Wk,
                                              const float *__restrict__ Wv,
                                              __bf16 *__restrict__ Wht,
                                              __bf16 *__restrict__ Wlt) {
  __shared__ float tile[32][256];
  const int wsel = blockIdx.x;
  const float *W = (wsel == 0) ? Wq : (wsel == 1) ? Wk : Wv;
  __bf16 *oh = Wht + wsel * HID * HID;
  __bf16 *ol = Wlt + wsel * HID * HID;
  const int t = threadIdx.x;
  for (int hb = 0; hb < 8; ++hb) {
    __syncthreads();
    #pragma unroll
    for (int p = 0; p < 8; ++p) {
      int r = p * 4 + (t >> 6);
      int c = (t & 63) * 4;
      *(floatx4 *)&tile[r][c] = *(const floatx4 *)&W[(hb * 32 + r) * HID + c];
    }
    __syncthreads();
    #pragma unroll
    for (int q = 0; q < 4; ++q) {
      int n = q * 64 + (t >> 2);
      int hs = (t & 3) * 8;
      bf16x8 hh, ll;
      #pragma unroll
      for (int i = 0; i < 8; ++i) {
        float v = tile[hs + i][n];
        __bf16 h, l;
        split_bf16(v, h, l);
        hh[i] = h; ll[i] = l;
      }
      *(bf16x8 *)&oh[n * HID + hb * 32 + hs] = hh;
      *(bf16x8 *)&ol[n * HID + hb * 32 + hs] = ll;
    }
  }
}

// ---------------------------------------------------------------------------
// Kernel 2: QKV projection (r4 version). W tiles in LDS (xor-swizzled);
// A-frags in regs. Epilogues: Q row-major hi/lo; K,V -> fragment-linear.
// ---------------------------------------------------------------------------
__global__ __launch_bounds__(256, 2) void qkv_proj(const float *__restrict__ X,
                                                   const __bf16 *__restrict__ Wht,
                                                   const __bf16 *__restrict__ Wlt,
                                                   __bf16 *__restrict__ Qh, __bf16 *__restrict__ Ql,
                                                   __bf16 *__restrict__ Kf,
                                                   __bf16 *__restrict__ Vf) {
  __shared__ __bf16 WhS[64 * 256];
  __shared__ __bf16 WlS[64 * 256];
  __bf16 *Th = WhS;
  __bf16 *Tl = WhS + 64 * 72;
  __bf16 *Tv = WhS;

  const int mtile = blockIdx.x;
  const int col0 = blockIdx.y * 64;
  const int tid = threadIdx.x;
  const int w4 = tid >> 6;
  const int lane = tid & 63;
  const int quad = lane >> 4;
  const int ln = lane & 15;
  const int arow = mtile * 64 + w4 * 16 + ln;

  bf16x8 ah[8], al[8];
  #pragma unroll
  for (int kc = 0; kc < 8; ++kc) {
    const float *xp = X + (size_t)arow * HID + kc * 32 + quad * 8;
    floatx4 x0 = *(const floatx4 *)xp;
    floatx4 x1 = *(const floatx4 *)(xp + 4);
    #pragma unroll
    for (int j = 0; j < 4; ++j) {
      __bf16 h, l;
      split_bf16(x0[j], h, l); ah[kc][j] = h; al[kc][j] = l;
      split_bf16(x1[j], h, l); ah[kc][4 + j] = h; al[kc][4 + j] = l;
    }
  }

  const int srow = tid >> 2;
  const int sseg = tid & 3;

  for (int w = 0; w < 3; ++w) {
    __syncthreads();
    const size_t wbase = (size_t)w * HID * HID + (size_t)(col0 + srow) * HID;
    #pragma unroll
    for (int j = 0; j < 8; ++j) {
      const int chunk = j * 4 + sseg;
      const int dst = srow * 256 + ((chunk ^ (srow & 7)) << 3);
      *(bf16x8 *)&WhS[dst] = *(const bf16x8 *)&Wht[wbase + chunk * 8];
      *(bf16x8 *)&WlS[dst] = *(const bf16x8 *)&Wlt[wbase + chunk * 8];
    }
    __syncthreads();

    floatx4 acc[4] = {};
    #pragma unroll
    for (int kc = 0; kc < 8; ++kc) {
      #pragma unroll
      for (int nt = 0; nt < 4; ++nt) {
        const int a = (nt * 16 + ln) * 256 + (((kc * 4 + quad) ^ (ln & 7)) << 3);
        bf16x8 bh = *(const bf16x8 *)&WhS[a];
        bf16x8 bl = *(const bf16x8 *)&WlS[a];
        acc[nt] = MFMA16(ah[kc], bh, acc[nt]);
        acc[nt] = MFMA16(ah[kc], bl, acc[nt]);
        acc[nt] = MFMA16(al[kc], bh, acc[nt]);
      }
    }

    if (w == 0) {
      #pragma unroll
      for (int nt = 0; nt < 4; ++nt) {
        #pragma unroll
        for (int r = 0; r < 4; ++r) {
          float v = acc[nt][r] * QSCALE;
          __bf16 h, l;
          split_bf16(v, h, l);
          const int orow = mtile * 64 + w4 * 16 + quad * 4 + r;
          const int ocol = col0 + nt * 16 + ln;
          Qh[(size_t)orow * HID + ocol] = h;
          Ql[(size_t)orow * HID + ocol] = l;
        }
      }
    } else if (w == 1) {
      __syncthreads();
      #pragma unroll
      for (int nt = 0; nt < 4; ++nt) {
        #pragma unroll
        for (int r = 0; r < 4; ++r) {
          __bf16 h, l;
          split_bf16(acc[nt][r], h, l);
          const int tok_l = w4 * 16 + quad * 4 + r;
          const int h_l = nt * 16 + ln;
          Th[tok_l * 72 + h_l] = h;
          Tl[tok_l * 72 + h_l] = l;
        }
      }
      __syncthreads();
      #pragma unroll
      for (int i = 0; i < 2; ++i) {
        const int c = i * 256 + tid;
        const int lane_f = c & 63;
        const int ntf = (c >> 6) & 1;
        const int kcL = (c >> 7) & 1;
        const int t2 = (c >> 8) & 1;
        const int qf = lane_f >> 4;
        const int lnf = lane_f & 15;
        const int tok_l = t2 * 32 + ntf * 16 + lnf;
        bf16x8 vh = *(const bf16x8 *)&Th[tok_l * 72 + kcL * 32 + qf * 8];
        bf16x8 vl = *(const bf16x8 *)&Tl[tok_l * 72 + kcL * 32 + qf * 8];
        const int T = mtile * 2 + t2;
        const int kc = (col0 >> 5) + kcL;
        const size_t dst = (size_t)T * 16384 + ((ntf * 8 + kc) * 64 + lane_f) * 8;
        *(bf16x8 *)&Kf[dst] = vh;
        *(bf16x8 *)&Kf[dst + 8192] = vl;
      }
    } else {
      __syncthreads();
      #pragma unroll
      for (int nt = 0; nt < 4; ++nt) {
        #pragma unroll
        for (int r = 0; r < 4; ++r) {
          const int tok_l = w4 * 16 + quad * 4 + r;
          const int d_l = nt * 16 + ln;
          Tv[d_l * 72 + tok_l] = (__bf16)acc[nt][r];
        }
      }
      __syncthreads();
      #pragma unroll
      for (int i = 0; i < 2; ++i) {
        const int c = i * 256 + tid;
        const int lane_f = c & 63;
        const int dtL = (c >> 6) & 3;
        const int t2 = (c >> 8) & 1;
        const int qf = lane_f >> 4;
        const int lnf = lane_f & 15;
        const int d_l = dtL * 16 + lnf;
        bf16x8 v = *(const bf16x8 *)&Tv[d_l * 72 + t2 * 32 + qf * 8];
        const int T = mtile * 2 + t2;
        const int dt = (col0 >> 4) + dtL;
        *(bf16x8 *)&Vf[(size_t)(T * 16 + dt) * 512 + lane_f * 8] = v;
      }
    }
  }
}

// ---------------------------------------------------------------------------
// Kernel 3: flash attention (r4 structure). grid = 512 (qt = bx>>1, ks = bx&1),
// 256 thr, 2 blocks/CU. K dbuf + linear memcpy staging; V direct from global;
// DPP softmax; 3-way QK chain split; P round-trip latency covered by rescale.
// ---------------------------------------------------------------------------
__global__ __launch_bounds__(256, 2) void attn(const __bf16 *__restrict__ QhG,
                                               const __bf16 *__restrict__ QlG,
                                               const __bf16 *__restrict__ Kf,
                                               const __bf16 *__restrict__ Vf,
                                               __bf16 *__restrict__ Op,
                                               float *__restrict__ Mp,
                                               float *__restrict__ Lp) {
  __shared__ __bf16 KS[2][16384];
  __shared__ __bf16 PsS[4 * 16 * 40];

  const int bx = blockIdx.x;
  const int ks = bx & 1;
  const int qt = bx >> 1;
  const int b = qt >> 6;
  const int qtl = qt & 63;
  const int tid = threadIdx.x;
  const int w4 = tid >> 6;
  const int lane = tid & 63;
  const int quad = lane >> 4;
  const int ln = lane & 15;
  const int T0 = b * 128 + ks * 64;

  const int qtok = b * LSEQ + qtl * 64 + w4 * 16 + ln;
  bf16x8 qh[8], ql[8];
  #pragma unroll
  for (int kc = 0; kc < 8; ++kc) {
    const size_t off = (size_t)qtok * HID + kc * 32 + quad * 8;
    qh[kc] = *(const bf16x8 *)&QhG[off];
    ql[kc] = *(const bf16x8 *)&QlG[off];
  }

  bf16x8 gk[8];
  {
    const __bf16 *src = Kf + (size_t)T0 * 16384 + tid * 8;
    #pragma unroll
    for (int i = 0; i < 8; ++i) gk[i] = *(const bf16x8 *)&src[i * 2048];
  }

  float m[4] = {-1e30f, -1e30f, -1e30f, -1e30f};
  float l[4] = {0.f, 0.f, 0.f, 0.f};
  floatx4 o[16] = {};

  for (int kt = 0; kt < 64; ++kt) {
    __bf16 *buf = KS[kt & 1];
    #pragma unroll
    for (int i = 0; i < 8; ++i)
      *(bf16x8 *)&buf[i * 2048 + tid * 8] = gk[i];
    __syncthreads();  // the only barrier per iter

    if (kt < 63) {
      const __bf16 *src = Kf + (size_t)(T0 + kt + 1) * 16384 + tid * 8;
      #pragma unroll
      for (int i = 0; i < 8; ++i) gk[i] = *(const bf16x8 *)&src[i * 2048];
    }

    const __bf16 *vsrc = Vf + (size_t)(T0 + kt) * 8192 + lane * 8;
    bf16x8 vb0[8];
    #pragma unroll
    for (int dt = 0; dt < 8; ++dt) vb0[dt] = *(const bf16x8 *)&vsrc[dt * 512];

    // ---- S = Q K^T : 3 independent 8-deep MFMA chains per nt ----
    floatx4 shh[2] = {}, shl[2] = {}, slh[2] = {};
    #pragma unroll
    for (int nt = 0; nt < 2; ++nt) {
      #pragma unroll
      for (int kc = 0; kc < 8; ++kc) {
        const __bf16 *kp = buf + (nt * 8 + kc) * 512 + lane * 8;
        bf16x8 bh = *(const bf16x8 *)kp;
        bf16x8 bl = *(const bf16x8 *)(kp + 8192);
        shh[nt] = MFMA16(qh[kc], bh, shh[nt]);
        shl[nt] = MFMA16(qh[kc], bl, shl[nt]);
        slh[nt] = MFMA16(ql[kc], bh, slh[nt]);
      }
    }
    floatx4 s[2];
    s[0] = (shl[0] + slh[0]) + shh[0];
    s[1] = (shl[1] + slh[1]) + shh[1];

    bf16x8 vb1[8];
    #pragma unroll
    for (int dt = 0; dt < 8; ++dt) vb1[dt] = *(const bf16x8 *)&vsrc[(8 + dt) * 512];

    // ---- online softmax (base-2), DPP 16-lane-row reductions ----
    float alpha[4];
    #pragma unroll
    for (int r = 0; r < 4; ++r) {
      const float tmax = row_max16(fmaxf(s[0][r], s[1][r]));
      const float mn = fmaxf(m[r], tmax);
      const float al = exp2f(m[r] - mn);
      const float p0 = exp2f(s[0][r] - mn);
      const float p1 = exp2f(s[1][r] - mn);
      s[0][r] = p0; s[1][r] = p1;
      const float rs = row_sum16(p0 + p1);
      l[r] = l[r] * al + rs;
      m[r] = mn;
      alpha[r] = al;
    }

    // ---- P write (C-layout -> A-layout via per-wave LDS) ----
    __bf16 *ps = PsS + w4 * 16 * 40;
    #pragma unroll
    for (int nt = 0; nt < 2; ++nt)
      #pragma unroll
      for (int r = 0; r < 4; ++r)
        ps[(quad * 4 + r) * 40 + nt * 16 + ln] = (__bf16)s[nt][r];

    // ---- O rescale (covers the ds_write -> ds_read latency) ----
    #pragma unroll
    for (int dt = 0; dt < 16; ++dt) {
      o[dt][0] *= alpha[0]; o[dt][1] *= alpha[1];
      o[dt][2] *= alpha[2]; o[dt][3] *= alpha[3];
    }

    const bf16x8 pa = *(const bf16x8 *)&ps[ln * 40 + quad * 8];

    // ---- O += P V ----
    #pragma unroll
    for (int dt = 0; dt < 8; ++dt) o[dt] = MFMA16(pa, vb0[dt], o[dt]);
    #pragma unroll
    for (int dt = 0; dt < 8; ++dt) o[8 + dt] = MFMA16(pa, vb1[dt], o[8 + dt]);
  }

  const int rowbase = b * LSEQ + qtl * 64 + w4 * 16 + quad * 4;
  #pragma unroll
  for (int dt = 0; dt < 16; ++dt)
    #pragma unroll
    for (int r = 0; r < 4; ++r)
      Op[(size_t)ks * PLANE + (size_t)(rowbase + r) * HID + dt * 16 + ln] = (__bf16)o[dt][r];
  if (ln == 0) {
    #pragma unroll
    for (int r = 0; r < 4; ++r) {
      Mp[ks * NTOK + rowbase + r] = m[r];
      Lp[ks * NTOK + rowbase + r] = l[r];
    }
  }
}

// ---------------------------------------------------------------------------
// Kernel 4: split-K merge.
// ---------------------------------------------------------------------------
__global__ __launch_bounds__(256) void merge(const __bf16 *__restrict__ Op,
                                             const float *__restrict__ Mp,
                                             const float *__restrict__ Lp,
                                             float *__restrict__ Out) {
  const int row = blockIdx.x * 4 + (threadIdx.x >> 6);
  const int c = (threadIdx.x & 63) * 4;
  const float m0 = Mp[row], m1 = Mp[NTOK + row];
  const float l0 = Lp[row], l1 = Lp[NTOK + row];
  const float M = fmaxf(m0, m1);
  const float e0 = exp2f(m0 - M), e1 = exp2f(m1 - M);
  const float invL = 1.0f / (l0 * e0 + l1 * e1);
  const float w0 = e0 * invL, w1 = e1 * invL;
  bf16x4 a = *(const bf16x4 *)&Op[(size_t)row * HID + c];
  bf16x4 b4 = *(const bf16x4 *)&Op[PLANE + (size_t)row * HID + c];
  floatx4 out;
  #pragma unroll
  for (int i = 0; i < 4; ++i) out[i] = w0 * (float)a[i] + w1 * (float)b4[i];
  *(floatx4 *)&Out[(size_t)row * HID + c] = out;
}

// ---------------------------------------------------------------------------
extern "C" void kernel_launch(void *const *d_in, const int *in_sizes, int n_in,
                              void *d_out, int out_size, void *d_ws, size_t ws_size,
                              hipStream_t stream) {
  const float *X = (const float *)d_in[0];
  const float *Wq = (const float *)d_in[1];
  const float *Wk = (const float *)d_in[2];
  const float *Wv = (const float *)d_in[3];
  // d_in[4] = lengths (unused by reference)

  __bf16 *ws = (__bf16 *)d_ws;
  __bf16 *Qh = ws;                           // [16384][256] row-major
  __bf16 *Ql = Qh + PLANE;
  __bf16 *Kf = Ql + PLANE;                   // frag-linear, 2*PLANE (hi+lo)
  __bf16 *Vf = Kf + 2 * PLANE;               // frag-linear, PLANE
  __bf16 *Wht = Vf + PLANE;                  // [3][256][256]
  __bf16 *Wlt = Wht + 3 * HID * HID;
  __bf16 *Op = Wlt + 3 * HID * HID;          // [2][16384][256] unnormalized
  float *Mp = (float *)(Op + 2 * PLANE);     // [2][16384]
  float *Lp = Mp + 2 * NTOK;                 // [2][16384]

  wsplit<<<3, 256, 0, stream>>>(Wq, Wk, Wv, Wht, Wlt);
  qkv_proj<<<dim3(256, 4), 256, 0, stream>>>(X, Wht, Wlt, Qh, Ql, Kf, Vf);
  attn<<<512, 256, 0, stream>>>(Qh, Ql, Kf, Vf, Op, Mp, Lp);
  merge<<<NTOK / 4, 256, 0, stream>>>(Op, Mp, Lp, (float *)d_out);
}